// Round 2
// baseline (4443.763 us; speedup 1.0000x reference)
//
#include <hip/hip_runtime.h>
#include <hip/hip_bf16.h>
#include <math.h>

#define N_NODES 50000
#define N_EDGES 1600000

struct GemmBatch {
  const float* W[4];
  const float* b[4];
  float* out[4];
};

// C[M,128] = A[M,K(lda)] @ W[K,128] + b ; one weight set per blockIdx.z
template<int K>
__global__ __launch_bounds__(256) void gemm128(const float* __restrict__ A, int lda, int M,
                                               GemmBatch gb) {
  const float* __restrict__ W    = gb.W[blockIdx.z];
  const float* __restrict__ bias = gb.b[blockIdx.z];
  float* __restrict__ out        = gb.out[blockIdx.z];
  __shared__ float xT[32][68];           // stride 68 floats -> 16B aligned rows
  int tid = threadIdx.x;
  int tc = tid & 31, tr = tid >> 5;
  int rbase = blockIdx.x * 64;
  float acc[8][4];
  #pragma unroll
  for (int i = 0; i < 8; i++)
    #pragma unroll
    for (int m = 0; m < 4; m++) acc[i][m] = 0.f;

  for (int kc = 0; kc < K; kc += 32) {
    {
      int c = tid & 31, rg = tid >> 5;
      #pragma unroll
      for (int i = 0; i < 8; i++) {
        int r = rg * 8 + i;
        int row = rbase + r; if (row >= M) row = M - 1;
        xT[c][r] = A[(size_t)row * lda + kc + c];
      }
    }
    __syncthreads();
    #pragma unroll
    for (int k = 0; k < 32; k++) {
      float4 x0 = *(const float4*)&xT[k][tr * 8];
      float4 x1 = *(const float4*)&xT[k][tr * 8 + 4];
      float w[4];
      #pragma unroll
      for (int m = 0; m < 4; m++) w[m] = W[(size_t)(kc + k) * 128 + tc + 32 * m];
      float xr[8] = {x0.x, x0.y, x0.z, x0.w, x1.x, x1.y, x1.z, x1.w};
      #pragma unroll
      for (int i = 0; i < 8; i++)
        #pragma unroll
        for (int m = 0; m < 4; m++)
          acc[i][m] = fmaf(xr[i], w[m], acc[i][m]);
    }
    __syncthreads();
  }
  #pragma unroll
  for (int m = 0; m < 4; m++) {
    float bb = bias[tc + 32 * m];
    #pragma unroll
    for (int i = 0; i < 8; i++) {
      int row = rbase + tr * 8 + i;
      if (row < M) out[(size_t)row * 128 + tc + 32 * m] = acc[i][m] + bb;
    }
  }
}

// e_sorted[epos[row]] = A[row] @ W + b   (edge input projection, scatter to CSR order)
template<int K>
__global__ __launch_bounds__(256) void gemm32_scatter(const float* __restrict__ A, int lda, int M,
                                                      const float* __restrict__ W,
                                                      const float* __restrict__ bias,
                                                      const int* __restrict__ epos,
                                                      float* __restrict__ out) {
  __shared__ float xT[32][132];
  int tid = threadIdx.x;
  int tc = tid & 31, tr = tid >> 5;      // tr 0..7 -> 16 rows each (128-row tile)
  int rbase = blockIdx.x * 128;
  float acc[16];
  #pragma unroll
  for (int i = 0; i < 16; i++) acc[i] = 0.f;

  for (int kc = 0; kc < K; kc += 32) {
    {
      int c = tid & 31, rg = tid >> 5;
      #pragma unroll
      for (int i = 0; i < 16; i++) {
        int r = rg * 16 + i;
        int row = rbase + r; if (row >= M) row = M - 1;
        xT[c][r] = A[(size_t)row * lda + kc + c];
      }
    }
    __syncthreads();
    #pragma unroll
    for (int k = 0; k < 32; k++) {
      float w = W[(size_t)(kc + k) * 32 + tc];
      #pragma unroll
      for (int u = 0; u < 4; u++) {
        float4 xv = *(const float4*)&xT[k][tr * 16 + 4 * u];
        acc[4*u+0] = fmaf(xv.x, w, acc[4*u+0]);
        acc[4*u+1] = fmaf(xv.y, w, acc[4*u+1]);
        acc[4*u+2] = fmaf(xv.z, w, acc[4*u+2]);
        acc[4*u+3] = fmaf(xv.w, w, acc[4*u+3]);
      }
    }
    __syncthreads();
  }
  float bb = bias[tc];
  #pragma unroll
  for (int i = 0; i < 16; i++) {
    int row = rbase + tr * 16 + i;
    if (row < M) {
      int orow = epos[row];
      out[(size_t)orow * 32 + tc] = acc[i] + bb;
    }
  }
}

// ---------------- CSR build ----------------
__global__ __launch_bounds__(256) void zero_deg(int* __restrict__ deg, int n) {
  int i = blockIdx.x * 256 + threadIdx.x;
  if (i < n) deg[i] = 0;
}

__global__ __launch_bounds__(256) void hist_kernel(const int* __restrict__ dst,
                                                   int* __restrict__ deg, int nE) {
  int i = blockIdx.x * 256 + threadIdx.x;
  if (i < nE) atomicAdd(&deg[dst[i]], 1);
}

__global__ __launch_bounds__(1024) void scan_kernel(const int* __restrict__ deg,
                                                    int* __restrict__ rowptr,
                                                    int* __restrict__ cursor, int n) {
  __shared__ int part[1024];
  int tid = threadIdx.x;
  const int CH = (n + 1023) / 1024;
  int base = tid * CH;
  int sum = 0;
  for (int i = 0; i < CH; i++) if (base + i < n) sum += deg[base + i];
  part[tid] = sum;
  __syncthreads();
  for (int off = 1; off < 1024; off <<= 1) {
    int v = (tid >= off) ? part[tid - off] : 0;
    __syncthreads();
    part[tid] += v;
    __syncthreads();
  }
  int run = (tid == 0) ? 0 : part[tid - 1];
  for (int i = 0; i < CH; i++) {
    int idx = base + i;
    if (idx < n) { rowptr[idx] = run; cursor[idx] = run; run += deg[idx]; }
  }
  if (tid == 1023) rowptr[n] = part[1023];
}

__global__ __launch_bounds__(256) void scatter_kernel(const int* __restrict__ src,
                                                      const int* __restrict__ dst,
                                                      int* __restrict__ cursor,
                                                      int* __restrict__ srcs,
                                                      int* __restrict__ epos, int nE) {
  int eid = blockIdx.x * 256 + threadIdx.x;
  if (eid < nE) {
    int d = dst[eid];
    int pos = atomicAdd(&cursor[d], 1);
    srcs[pos] = src[eid];
    epos[eid] = pos;
  }
}

// ---------------- fused aggregation + skip + LayerNorm ----------------
// 2 dst nodes per block, 128 threads per node (thread j owns column j).
// For each in-edge p of node d: el = e_s[p] @ Wed + bed;
//   gate = sigmoid(k[d] + q[srcs[p]] + el); acc += gate * v[srcs[p]]
// h = acc + skip[d]; LayerNorm(h) -> out slice.
__global__ __launch_bounds__(256) void agg_ln_kernel(
    const float* __restrict__ e_s, const int* __restrict__ srcs,
    const int* __restrict__ rowptr,
    const float* __restrict__ kf, const float* __restrict__ qf,
    const float* __restrict__ vf, const float* __restrict__ skip,
    const float* __restrict__ Wed, const float* __restrict__ bed,
    const float* __restrict__ g, const float* __restrict__ b,
    float* __restrict__ out, int ldo, int M) {
  __shared__ float wlds[32 * 128];       // 16 KB
  __shared__ float red[2][2][2];
  int tid = threadIdx.x;
  #pragma unroll
  for (int t = 0; t < 16; t++) wlds[tid + 256 * t] = Wed[tid + 256 * t];
  __syncthreads();

  int j   = tid & 127;
  int sub = tid >> 7;                    // node slot within block
  int node = blockIdx.x * 2 + sub;
  float bj = bed[j];
  float acc = 0.f;
  float hval = 0.f;

  if (node < M) {
    int p0 = rowptr[node], p1 = rowptr[node + 1];
    float kd = kf[(size_t)node * 128 + j];
    float qs = 0.f, vs = 0.f;
    if (p0 < p1) {
      int s0 = srcs[p0];
      qs = qf[(size_t)s0 * 128 + j];
      vs = vf[(size_t)s0 * 128 + j];
    }
    for (int p = p0; p < p1; p++) {
      // prefetch next edge's gathers to overlap with el FMA chain
      float qn = 0.f, vn = 0.f;
      if (p + 1 < p1) {
        int sn = srcs[p + 1];
        qn = qf[(size_t)sn * 128 + j];
        vn = vf[(size_t)sn * 128 + j];
      }
      const float4* er = (const float4*)(e_s + (size_t)p * 32);
      float el = bj;
      #pragma unroll
      for (int t = 0; t < 8; t++) {
        float4 ev = er[t];
        el = fmaf(ev.x, wlds[(4*t+0)*128 + j], el);
        el = fmaf(ev.y, wlds[(4*t+1)*128 + j], el);
        el = fmaf(ev.z, wlds[(4*t+2)*128 + j], el);
        el = fmaf(ev.w, wlds[(4*t+3)*128 + j], el);
      }
      float t_  = kd + qs + el;
      float u   = __expf(-t_);
      float gsg = __builtin_amdgcn_rcpf(1.0f + u);
      acc = fmaf(gsg, vs, acc);
      qs = qn; vs = vn;
    }
    hval = acc + skip[(size_t)node * 128 + j];
  }

  // LayerNorm over the 128 columns of this node (2 waves)
  float s = hval, ss = hval * hval;
  #pragma unroll
  for (int off = 32; off; off >>= 1) {
    s  += __shfl_xor(s, off);
    ss += __shfl_xor(ss, off);
  }
  int wv = (tid >> 6) & 1;
  if ((tid & 63) == 0) { red[sub][wv][0] = s; red[sub][wv][1] = ss; }
  __syncthreads();
  float S  = red[sub][0][0] + red[sub][1][0];
  float SS = red[sub][0][1] + red[sub][1][1];
  float mean = S * (1.f / 128.f);
  float var  = SS * (1.f / 128.f) - mean * mean;
  float rstd = rsqrtf(var + 1e-5f);
  if (node < M)
    out[(size_t)node * ldo + j] = (hval - mean) * rstd * g[j] + b[j];
}

extern "C" void kernel_launch(void* const* d_in, const int* in_sizes, int n_in,
                              void* d_out, int out_size, void* d_ws, size_t ws_size,
                              hipStream_t stream) {
  const float* nf  = (const float*)d_in[0];
  const int*   ei  = (const int*)  d_in[1];
  const float* ea  = (const float*)d_in[2];
  const float* Wn  = (const float*)d_in[3];
  const float* bn  = (const float*)d_in[4];
  const float* We  = (const float*)d_in[5];
  const float* be  = (const float*)d_in[6];
  const float* Wk  = (const float*)d_in[7];
  const float* bk  = (const float*)d_in[8];
  const float* Wq  = (const float*)d_in[9];
  const float* bq  = (const float*)d_in[10];
  const float* Wv  = (const float*)d_in[11];
  const float* bv  = (const float*)d_in[12];
  const float* Wed = (const float*)d_in[13];
  const float* bed = (const float*)d_in[14];
  const float* Wsk = (const float*)d_in[15];
  const float* cb  = (const float*)d_in[16];
  const float* lng = (const float*)d_in[17];
  const float* lnb = (const float*)d_in[18];
  const float* Wh  = (const float*)d_in[19];
  const float* bh  = (const float*)d_in[20];
  float* out = (float*)d_out;

  float* ws  = (float*)d_ws;
  float* x0  = ws;                                  // N*128
  float* e_s = x0  + (size_t)N_NODES * 128;         // E*32 (dst-sorted)
  float* kf  = e_s + (size_t)N_EDGES * 32;          // N*128
  float* qf  = kf  + (size_t)N_NODES * 128;         // N*128
  float* vf  = qf  + (size_t)N_NODES * 128;         // N*128
  float* agg = vf  + (size_t)N_NODES * 128;         // N*128 (holds skip = x@Wskip+cb)
  float* hid = agg + (size_t)N_NODES * 128;         // N*384
  int*   ip  = (int*)(hid + (size_t)N_NODES * 384);
  int* deg    = ip;                                 // N
  int* rowptr = deg + N_NODES;                      // N+1
  int* cursor = rowptr + N_NODES + 1;               // N
  int* srcs   = cursor + N_NODES;                   // E
  int* epos   = srcs + N_EDGES;                     // E

  const int* srcp = ei;
  const int* dstp = ei + N_EDGES;

  dim3 blk(256);
  int gN = (N_NODES + 63) / 64;
  int gE = (N_EDGES + 255) / 256;

  // CSR build (dst-sorted)
  zero_deg<<<dim3((N_NODES + 255) / 256), blk, 0, stream>>>(deg, N_NODES);
  hist_kernel<<<dim3(gE), blk, 0, stream>>>(dstp, deg, N_EDGES);
  scan_kernel<<<dim3(1), dim3(1024), 0, stream>>>(deg, rowptr, cursor, N_NODES);
  scatter_kernel<<<dim3(gE), blk, 0, stream>>>(srcp, dstp, cursor, srcs, epos, N_EDGES);

  // input projections
  { GemmBatch gb{}; gb.W[0] = Wn; gb.b[0] = bn; gb.out[0] = x0;
    gemm128<256><<<dim3(gN, 1, 1), blk, 0, stream>>>(nf, 256, N_NODES, gb); }
  gemm32_scatter<64><<<dim3(N_EDGES / 128), blk, 0, stream>>>(ea, 64, N_EDGES, We, be, epos, e_s);

  const float* xcur = x0; int ldx = 128;
  for (int i = 0; i < 3; i++) {
    GemmBatch gb{};
    gb.W[0] = Wk  + (size_t)i * 128 * 128; gb.b[0] = bk + i * 128; gb.out[0] = kf;
    gb.W[1] = Wq  + (size_t)i * 128 * 128; gb.b[1] = bq + i * 128; gb.out[1] = qf;
    gb.W[2] = Wv  + (size_t)i * 128 * 128; gb.b[2] = bv + i * 128; gb.out[2] = vf;
    gb.W[3] = Wsk + (size_t)i * 128 * 128; gb.b[3] = cb + i * 128; gb.out[3] = agg;
    gemm128<128><<<dim3(gN, 1, 4), blk, 0, stream>>>(xcur, ldx, N_NODES, gb);

    agg_ln_kernel<<<dim3((N_NODES + 1) / 2), blk, 0, stream>>>(
        e_s, srcs, rowptr, kf, qf, vf, agg,
        Wed + (size_t)i * 32 * 128, bed + i * 128,
        lng + i * 128, lnb + i * 128,
        hid + i * 128, 384, N_NODES);

    xcur = hid + i * 128; ldx = 384;
  }

  { GemmBatch gb{}; gb.W[0] = Wh; gb.b[0] = bh; gb.out[0] = out;
    gemm128<384><<<dim3(gN, 1, 1), blk, 0, stream>>>(hid, 384, N_NODES, gb); }
}